// Round 1
// baseline (19995.261 us; speedup 1.0000x reference)
//
#include <hip/hip_runtime.h>
#include <hip/hip_cooperative_groups.h>

namespace cg = cooperative_groups;

// T=256, B=128, H=2048. M = T*B = 32768.
// ws layout (bytes):
//   XP     @ 0          : 32768*2048*2 = 134217728   (xproj, bf16, [t*128+b][h])
//   WT_in  @ 134217728  : 2048*2048*2  = 8388608     (w_in^T bf16, [n][k])
//   WT_rec @ 142606336  : 8388608                    (w_rec^T bf16, [n][k])
//   hA     @ 150994944  : 128*2048*2   = 524288      (h written at even t)
//   hB     @ 151519232  : 524288                     (h written at odd t)
// total 152043520 bytes — assumes ws_size >= ~145 MB.

typedef __bf16 bf16x8 __attribute__((ext_vector_type(8)));
typedef float f32x4 __attribute__((ext_vector_type(4)));

__device__ __forceinline__ unsigned short f32_to_bf16(float f) {
    unsigned int u = __builtin_bit_cast(unsigned int, f);
    u += 0x7FFFu + ((u >> 16) & 1u);   // round-to-nearest-even
    return (unsigned short)(u >> 16);
}
__device__ __forceinline__ float bf16_to_f32(unsigned short s) {
    unsigned int u = ((unsigned int)s) << 16;
    return __builtin_bit_cast(float, u);
}

// ---------------------------------------------------------------------------
// Kernel 1: fp32 (2048x2048, [k][n]) -> bf16 transposed ([n][k]) via LDS tile.
// grid 1024 x 256 threads; 64x64 tiles.
// ---------------------------------------------------------------------------
__global__ __launch_bounds__(256)
void cvt_transpose(const float* __restrict__ W, unsigned short* __restrict__ WT) {
    __shared__ unsigned short tile[64][68];  // +4 pad breaks bank alignment
    const int tid = threadIdx.x;
    const int n0 = (blockIdx.x & 31) * 64;
    const int k0 = (blockIdx.x >> 5) * 64;
    const int rr = tid >> 4;          // 0..15
    const int cc = (tid & 15) * 4;    // 0..60
#pragma unroll
    for (int p = 0; p < 4; ++p) {
        const int k = rr + p * 16;
        const float4 v = *(const float4*)(W + (size_t)(k0 + k) * 2048 + n0 + cc);
        tile[cc + 0][k] = f32_to_bf16(v.x);
        tile[cc + 1][k] = f32_to_bf16(v.y);
        tile[cc + 2][k] = f32_to_bf16(v.z);
        tile[cc + 3][k] = f32_to_bf16(v.w);
    }
    __syncthreads();
#pragma unroll
    for (int p = 0; p < 4; ++p) {
        const int n = rr + p * 16;
        unsigned int lo = (unsigned int)tile[n][cc]     | ((unsigned int)tile[n][cc + 1] << 16);
        unsigned int hi = (unsigned int)tile[n][cc + 2] | ((unsigned int)tile[n][cc + 3] << 16);
        uint2 ov; ov.x = lo; ov.y = hi;
        *(uint2*)(WT + (size_t)(n0 + n) * 2048 + k0 + cc) = ov;
    }
}

// ---------------------------------------------------------------------------
// Kernel 2: xproj GEMM. C[m][n] = sum_k X[m][k] * w_in[k][n], stored bf16.
// X fp32 (32768x2048) converted to bf16 during LDS staging; WT bf16 [n][k].
// 128x128 tile, BK=32, 4 waves each 64x64 (4x4 accumulators of 16x16x32 MFMA).
// grid 4096 (mb = bid>>4, nb = bid&15) x 256 threads.
// ---------------------------------------------------------------------------
__global__ __launch_bounds__(256, 2)
void xproj_gemm(const float* __restrict__ X, const unsigned short* __restrict__ WT,
                unsigned short* __restrict__ XP) {
    __shared__ unsigned short As[128 * 32];  // [m][k], 32-elem rows
    __shared__ unsigned short Bs[128 * 32];  // [n][k], 32-elem rows
    const int tid  = threadIdx.x;
    const int bid  = blockIdx.x;
    const int m0   = (bid >> 4) * 128;
    const int n0   = (bid & 15) * 128;
    const int lane = tid & 63;
    const int wave = tid >> 6;
    const int wm   = (wave & 1) * 64;
    const int wn   = (wave >> 1) * 64;
    const int lcol = lane & 15;
    const int quad = lane >> 4;

    const int ar = tid >> 3;          // A stage: 0..31 (4 passes of 32 rows)
    const int ac = (tid & 7) * 4;     // 8 threads x float4 per 32-elem row
    const int br = tid >> 1;          // B stage: 0..127
    const int bc = (tid & 1) * 16;    // 2 threads x 16 elems per row

    f32x4 acc[4][4] = {};

    for (int kk = 0; kk < 2048; kk += 32) {
        // stage A: fp32 -> bf16
#pragma unroll
        for (int p = 0; p < 4; ++p) {
            const int r = ar + p * 32;
            const float4 v = *(const float4*)(X + (size_t)(m0 + r) * 2048 + kk + ac);
            unsigned int lo = (unsigned int)f32_to_bf16(v.x) | ((unsigned int)f32_to_bf16(v.y) << 16);
            unsigned int hi = (unsigned int)f32_to_bf16(v.z) | ((unsigned int)f32_to_bf16(v.w) << 16);
            uint2 w; w.x = lo; w.y = hi;
            *(uint2*)(As + r * 32 + ac) = w;
        }
        // stage B: bf16 copy (already [n][k])
        {
            const unsigned short* g = WT + (size_t)(n0 + br) * 2048 + kk + bc;
            const uint4 v0 = *(const uint4*)(g);
            const uint4 v1 = *(const uint4*)(g + 8);
            *(uint4*)(Bs + br * 32 + bc)     = v0;
            *(uint4*)(Bs + br * 32 + bc + 8) = v1;
        }
        __syncthreads();
        bf16x8 af[4], bf[4];
#pragma unroll
        for (int i = 0; i < 4; ++i)
            af[i] = __builtin_bit_cast(bf16x8, *(const uint4*)(As + (wm + i * 16 + lcol) * 32 + quad * 8));
#pragma unroll
        for (int j = 0; j < 4; ++j)
            bf[j] = __builtin_bit_cast(bf16x8, *(const uint4*)(Bs + (wn + j * 16 + lcol) * 32 + quad * 8));
#pragma unroll
        for (int i = 0; i < 4; ++i)
#pragma unroll
            for (int j = 0; j < 4; ++j)
                acc[i][j] = __builtin_amdgcn_mfma_f32_16x16x32_bf16(af[i], bf[j], acc[i][j], 0, 0, 0);
        __syncthreads();
    }
    // epilogue: C/D layout col=lane&15, row=quad*4+reg
#pragma unroll
    for (int i = 0; i < 4; ++i)
#pragma unroll
        for (int j = 0; j < 4; ++j) {
            const int row = m0 + wm + i * 16 + quad * 4;
            const int col = n0 + wn + j * 16 + lcol;
#pragma unroll
            for (int r = 0; r < 4; ++r)
                XP[(size_t)(row + r) * 2048 + col] = f32_to_bf16(acc[i][j][r]);
        }
}

// ---------------------------------------------------------------------------
// Kernel 3: persistent cooperative recurrence. 256 blocks x 256 threads.
// Block (nb = bid>>2, bb = bid&3) owns output tile [bb*32..+32) x [nb*32..+32).
// w_rec^T slice (32 cols x 2048 k, bf16) LDS-resident for all 256 steps.
// 4 waves split K (512 each); each wave 2x2 MFMA accumulators; LDS reduce.
// h double-buffered bf16 in global; grid.sync() per step.
// ---------------------------------------------------------------------------
__global__ __launch_bounds__(256, 1)
void rnn_scan(const unsigned short* __restrict__ XP,
              const unsigned short* __restrict__ WT,
              const float* __restrict__ bias,
              unsigned short* __restrict__ hA,
              unsigned short* __restrict__ hB,
              float* __restrict__ out) {
    __shared__ unsigned short Ws[32 * 2056];  // rows padded 2048 -> 2056 elems
    __shared__ float red[4 * 1024];           // 4 wave-partials of 32x32
    const int tid  = threadIdx.x;
    const int bid  = blockIdx.x;
    const int n0   = (bid >> 2) * 32;
    const int m0   = (bid & 3) * 32;
    const int lane = tid & 63;
    const int wave = tid >> 6;
    const int lcol = lane & 15;
    const int quad = lane >> 4;

    // load w_rec^T slice into LDS (coalesced 16B chunks)
    {
        const int r  = tid >> 3;          // 0..31 (local n)
        const int ch = (tid & 7) * 256;   // elem offset within the 2048-k row
        const unsigned short* src = WT + (size_t)(n0 + r) * 2048 + ch;
        unsigned short* dst = Ws + r * 2056 + ch;
#pragma unroll
        for (int c = 0; c < 32; ++c)
            *(uint4*)(dst + c * 8) = *(const uint4*)(src + c * 8);
    }
    const int erow = tid >> 3;          // epilogue: 4 elems per thread
    const int ecol = (tid & 7) * 4;
    const float4 b4 = *(const float4*)(bias + n0 + ecol);
    cg::grid_group grid = cg::this_grid();
    __syncthreads();

    const int kb = wave * 512;
    for (int t = 0; t < 256; ++t) {
        // prefetch this step's xproj tile (hidden under the GEMM)
        const uint2 xpu = *(const uint2*)(XP + (size_t)(t * 128 + m0 + erow) * 2048 + n0 + ecol);
        float4 sum = {0.f, 0.f, 0.f, 0.f};
        if (t > 0) {
            const unsigned short* hprev = (t & 1) ? hA : hB;
            f32x4 a00 = {}, a01 = {}, a10 = {}, a11 = {};
            const unsigned short* a0p = hprev + (size_t)(m0 + lcol) * 2048 + kb + quad * 8;
            const unsigned short* a1p = a0p + 16 * 2048;
            const unsigned short* b0p = Ws + lcol * 2056 + kb + quad * 8;
            const unsigned short* b1p = b0p + 16 * 2056;
#pragma unroll
            for (int it = 0; it < 16; ++it) {
                const int ko = it * 32;
                bf16x8 a0 = __builtin_bit_cast(bf16x8, *(const uint4*)(a0p + ko));
                bf16x8 a1 = __builtin_bit_cast(bf16x8, *(const uint4*)(a1p + ko));
                bf16x8 b0 = __builtin_bit_cast(bf16x8, *(const uint4*)(b0p + ko));
                bf16x8 b1 = __builtin_bit_cast(bf16x8, *(const uint4*)(b1p + ko));
                a00 = __builtin_amdgcn_mfma_f32_16x16x32_bf16(a0, b0, a00, 0, 0, 0);
                a01 = __builtin_amdgcn_mfma_f32_16x16x32_bf16(a0, b1, a01, 0, 0, 0);
                a10 = __builtin_amdgcn_mfma_f32_16x16x32_bf16(a1, b0, a10, 0, 0, 0);
                a11 = __builtin_amdgcn_mfma_f32_16x16x32_bf16(a1, b1, a11, 0, 0, 0);
            }
            float* rw = red + wave * 1024;
#pragma unroll
            for (int r = 0; r < 4; ++r) {
                rw[(quad * 4 + r) * 32 + lcol]           = a00[r];
                rw[(quad * 4 + r) * 32 + 16 + lcol]      = a01[r];
                rw[(16 + quad * 4 + r) * 32 + lcol]      = a10[r];
                rw[(16 + quad * 4 + r) * 32 + 16 + lcol] = a11[r];
            }
            __syncthreads();
            const float4 s0 = *(const float4*)(red + 0 * 1024 + tid * 4);
            const float4 s1 = *(const float4*)(red + 1 * 1024 + tid * 4);
            const float4 s2 = *(const float4*)(red + 2 * 1024 + tid * 4);
            const float4 s3 = *(const float4*)(red + 3 * 1024 + tid * 4);
            sum.x = (s0.x + s1.x) + (s2.x + s3.x);
            sum.y = (s0.y + s1.y) + (s2.y + s3.y);
            sum.z = (s0.z + s1.z) + (s2.z + s3.z);
            sum.w = (s0.w + s1.w) + (s2.w + s3.w);
        }
        float4 v;
        v.x = tanhf(bf16_to_f32((unsigned short)(xpu.x & 0xFFFFu)) + sum.x + b4.x);
        v.y = tanhf(bf16_to_f32((unsigned short)(xpu.x >> 16))     + sum.y + b4.y);
        v.z = tanhf(bf16_to_f32((unsigned short)(xpu.y & 0xFFFFu)) + sum.z + b4.z);
        v.w = tanhf(bf16_to_f32((unsigned short)(xpu.y >> 16))     + sum.w + b4.w);
        if (t < 255) {
            unsigned short* hc = (t & 1) ? hB : hA;
            unsigned int p0 = (unsigned int)f32_to_bf16(v.x) | ((unsigned int)f32_to_bf16(v.y) << 16);
            unsigned int p1 = (unsigned int)f32_to_bf16(v.z) | ((unsigned int)f32_to_bf16(v.w) << 16);
            uint2 pv; pv.x = p0; pv.y = p1;
            *(uint2*)(hc + (size_t)(m0 + erow) * 2048 + n0 + ecol) = pv;
            __threadfence();   // cross-XCD visibility (release)
            grid.sync();       // also covers 'red' reuse (block-level)
            __threadfence();   // acquire side, belt-and-braces
        } else {
            *(float4*)(out + (size_t)(m0 + erow) * 2048 + n0 + ecol) = v;
        }
    }
}

// ---------------------------------------------------------------------------
extern "C" void kernel_launch(void* const* d_in, const int* in_sizes, int n_in,
                              void* d_out, int out_size, void* d_ws, size_t ws_size,
                              hipStream_t stream) {
    const float* x     = (const float*)d_in[0];   // (256,128,2048)
    const float* w_in  = (const float*)d_in[1];   // (2048,2048) [k][n]
    const float* w_rec = (const float*)d_in[2];   // (2048,2048) [k][n]
    const float* bias  = (const float*)d_in[3];   // (2048,)
    float* out = (float*)d_out;                   // (128,2048) fp32

    char* ws = (char*)d_ws;
    unsigned short* XP     = (unsigned short*)(ws);
    unsigned short* WT_in  = (unsigned short*)(ws + 134217728);
    unsigned short* WT_rec = (unsigned short*)(ws + 134217728 + 8388608);
    unsigned short* hA     = (unsigned short*)(ws + 150994944);
    unsigned short* hB     = (unsigned short*)(ws + 150994944 + 524288);

    cvt_transpose<<<dim3(1024), dim3(256), 0, stream>>>(w_in,  WT_in);
    cvt_transpose<<<dim3(1024), dim3(256), 0, stream>>>(w_rec, WT_rec);
    xproj_gemm<<<dim3(4096), dim3(256), 0, stream>>>(x, WT_in, XP);

    void* args[] = {(void*)&XP, (void*)&WT_rec, (void*)&bias,
                    (void*)&hA, (void*)&hB, (void*)&out};
    hipLaunchCooperativeKernel(reinterpret_cast<void*>(rnn_scan),
                               dim3(256), dim3(256), args, 0, stream);
}

// Round 2
// 12187.870 us; speedup vs baseline: 1.6406x; 1.6406x over previous
//
#include <hip/hip_runtime.h>

// T=256, B=128, H=2048. M = T*B = 32768.
// ws layout (bytes):
//   XP     @ 0          : 32768*2048*2 = 134217728   (xproj, bf16, [t*128+b][h])
//   WT_in  @ 134217728  : 2048*2048*2  = 8388608     (w_in^T bf16, [n][k])
//   WT_rec @ 142606336  : 8388608                    (w_rec^T bf16, [n][k])
//   hA     @ 150994944  : 128*2048*2   = 524288      (h written at even t)
//   hB     @ 151519232  : 524288                     (h written at odd t)
//   BAR    @ 152043520  : 4 groups * 256 B = 1024    (barrier counters)
// total ~152 MB.

typedef __bf16 bf16x8 __attribute__((ext_vector_type(8)));
typedef float f32x4 __attribute__((ext_vector_type(4)));

__device__ __forceinline__ unsigned short f32_to_bf16(float f) {
    unsigned int u = __builtin_bit_cast(unsigned int, f);
    u += 0x7FFFu + ((u >> 16) & 1u);   // round-to-nearest-even
    return (unsigned short)(u >> 16);
}
__device__ __forceinline__ float bf16_to_f32(unsigned short s) {
    unsigned int u = ((unsigned int)s) << 16;
    return __builtin_bit_cast(float, u);
}

// ---------------------------------------------------------------------------
// Kernel 1: fp32 (2048x2048, [k][n]) -> bf16 transposed ([n][k]) via LDS tile.
// ---------------------------------------------------------------------------
__global__ __launch_bounds__(256)
void cvt_transpose(const float* __restrict__ W, unsigned short* __restrict__ WT) {
    __shared__ unsigned short tile[64][68];
    const int tid = threadIdx.x;
    const int n0 = (blockIdx.x & 31) * 64;
    const int k0 = (blockIdx.x >> 5) * 64;
    const int rr = tid >> 4;
    const int cc = (tid & 15) * 4;
#pragma unroll
    for (int p = 0; p < 4; ++p) {
        const int k = rr + p * 16;
        const float4 v = *(const float4*)(W + (size_t)(k0 + k) * 2048 + n0 + cc);
        tile[cc + 0][k] = f32_to_bf16(v.x);
        tile[cc + 1][k] = f32_to_bf16(v.y);
        tile[cc + 2][k] = f32_to_bf16(v.z);
        tile[cc + 3][k] = f32_to_bf16(v.w);
    }
    __syncthreads();
#pragma unroll
    for (int p = 0; p < 4; ++p) {
        const int n = rr + p * 16;
        unsigned int lo = (unsigned int)tile[n][cc]     | ((unsigned int)tile[n][cc + 1] << 16);
        unsigned int hi = (unsigned int)tile[n][cc + 2] | ((unsigned int)tile[n][cc + 3] << 16);
        uint2 ov; ov.x = lo; ov.y = hi;
        *(uint2*)(WT + (size_t)(n0 + n) * 2048 + k0 + cc) = ov;
    }
}

// ---------------------------------------------------------------------------
// Kernel 2: xproj GEMM. C[m][n] = sum_k X[m][k] * w_in[k][n], stored bf16.
// 128x128 tile, BK=32, 4 waves each 64x64. grid 4096 x 256.
// ---------------------------------------------------------------------------
__global__ __launch_bounds__(256, 2)
void xproj_gemm(const float* __restrict__ X, const unsigned short* __restrict__ WT,
                unsigned short* __restrict__ XP) {
    __shared__ unsigned short As[128 * 32];
    __shared__ unsigned short Bs[128 * 32];
    const int tid  = threadIdx.x;
    const int bid  = blockIdx.x;
    const int m0   = (bid >> 4) * 128;
    const int n0   = (bid & 15) * 128;
    const int lane = tid & 63;
    const int wave = tid >> 6;
    const int wm   = (wave & 1) * 64;
    const int wn   = (wave >> 1) * 64;
    const int lcol = lane & 15;
    const int quad = lane >> 4;

    const int ar = tid >> 3;
    const int ac = (tid & 7) * 4;
    const int br = tid >> 1;
    const int bc = (tid & 1) * 16;

    f32x4 acc[4][4] = {};

    for (int kk = 0; kk < 2048; kk += 32) {
#pragma unroll
        for (int p = 0; p < 4; ++p) {
            const int r = ar + p * 32;
            const float4 v = *(const float4*)(X + (size_t)(m0 + r) * 2048 + kk + ac);
            unsigned int lo = (unsigned int)f32_to_bf16(v.x) | ((unsigned int)f32_to_bf16(v.y) << 16);
            unsigned int hi = (unsigned int)f32_to_bf16(v.z) | ((unsigned int)f32_to_bf16(v.w) << 16);
            uint2 w; w.x = lo; w.y = hi;
            *(uint2*)(As + r * 32 + ac) = w;
        }
        {
            const unsigned short* g = WT + (size_t)(n0 + br) * 2048 + kk + bc;
            const uint4 v0 = *(const uint4*)(g);
            const uint4 v1 = *(const uint4*)(g + 8);
            *(uint4*)(Bs + br * 32 + bc)     = v0;
            *(uint4*)(Bs + br * 32 + bc + 8) = v1;
        }
        __syncthreads();
        bf16x8 af[4], bf[4];
#pragma unroll
        for (int i = 0; i < 4; ++i)
            af[i] = __builtin_bit_cast(bf16x8, *(const uint4*)(As + (wm + i * 16 + lcol) * 32 + quad * 8));
#pragma unroll
        for (int j = 0; j < 4; ++j)
            bf[j] = __builtin_bit_cast(bf16x8, *(const uint4*)(Bs + (wn + j * 16 + lcol) * 32 + quad * 8));
#pragma unroll
        for (int i = 0; i < 4; ++i)
#pragma unroll
            for (int j = 0; j < 4; ++j)
                acc[i][j] = __builtin_amdgcn_mfma_f32_16x16x32_bf16(af[i], bf[j], acc[i][j], 0, 0, 0);
        __syncthreads();
    }
#pragma unroll
    for (int i = 0; i < 4; ++i)
#pragma unroll
        for (int j = 0; j < 4; ++j) {
            const int row = m0 + wm + i * 16 + quad * 4;
            const int col = n0 + wn + j * 16 + lcol;
#pragma unroll
            for (int r = 0; r < 4; ++r)
                XP[(size_t)(row + r) * 2048 + col] = f32_to_bf16(acc[i][j][r]);
        }
}

// ---------------------------------------------------------------------------
// Kernel 3: persistent recurrence. 256 blocks x 256 threads (coop launch for
// co-residency only). Block (nb = bid>>2, bb = bid&3) owns output tile
// [bb*32 batches) x [nb*32 cols). Batch groups are INDEPENDENT recurrences,
// so sync is per-group: 4 monotonic barriers of 64 blocks each, relaxed
// agent-scope polls (no per-poll cache inv), one release fence before
// arrival, one acquire fence after.
// ---------------------------------------------------------------------------
__global__ __launch_bounds__(256, 1)
void rnn_scan(const unsigned short* __restrict__ XP,
              const unsigned short* __restrict__ WT,
              const float* __restrict__ bias,
              unsigned short* __restrict__ hA,
              unsigned short* __restrict__ hB,
              float* __restrict__ out,
              unsigned int* __restrict__ bar) {
    __shared__ unsigned short Ws[32 * 2056];  // 32 cols x 2048 k, rows padded
    __shared__ float red[4 * 1024];           // 4 wave-partials of 32x32
    const int tid  = threadIdx.x;
    const int bid  = blockIdx.x;
    const int n0   = (bid >> 2) * 32;
    const int m0   = (bid & 3) * 32;
    const int lane = tid & 63;
    const int wave = tid >> 6;
    const int lcol = lane & 15;
    const int quad = lane >> 4;
    unsigned int* cnt = bar + (bid & 3) * 64;   // 256 B apart per group

    // load w_rec^T slice into LDS
    {
        const int r  = tid >> 3;
        const int ch = (tid & 7) * 256;
        const unsigned short* src = WT + (size_t)(n0 + r) * 2048 + ch;
        unsigned short* dst = Ws + r * 2056 + ch;
#pragma unroll
        for (int c = 0; c < 32; ++c)
            *(uint4*)(dst + c * 8) = *(const uint4*)(src + c * 8);
    }
    const int erow = tid >> 3;
    const int ecol = (tid & 7) * 4;
    const float4 b4 = *(const float4*)(bias + n0 + ecol);
    __syncthreads();

    const int kb = wave * 512;
    for (int t = 0; t < 256; ++t) {
        const uint2 xpu = *(const uint2*)(XP + (size_t)(t * 128 + m0 + erow) * 2048 + n0 + ecol);
        float4 sum = {0.f, 0.f, 0.f, 0.f};
        if (t > 0) {
            const unsigned short* hprev = (t & 1) ? hA : hB;
            f32x4 a00 = {}, a01 = {}, a10 = {}, a11 = {};
            const unsigned short* a0p = hprev + (size_t)(m0 + lcol) * 2048 + kb + quad * 8;
            const unsigned short* a1p = a0p + 16 * 2048;
            const unsigned short* b0p = Ws + lcol * 2056 + kb + quad * 8;
            const unsigned short* b1p = b0p + 16 * 2056;
#pragma unroll
            for (int it = 0; it < 16; ++it) {
                const int ko = it * 32;
                bf16x8 a0 = __builtin_bit_cast(bf16x8, *(const uint4*)(a0p + ko));
                bf16x8 a1 = __builtin_bit_cast(bf16x8, *(const uint4*)(a1p + ko));
                bf16x8 b0 = __builtin_bit_cast(bf16x8, *(const uint4*)(b0p + ko));
                bf16x8 b1 = __builtin_bit_cast(bf16x8, *(const uint4*)(b1p + ko));
                a00 = __builtin_amdgcn_mfma_f32_16x16x32_bf16(a0, b0, a00, 0, 0, 0);
                a01 = __builtin_amdgcn_mfma_f32_16x16x32_bf16(a0, b1, a01, 0, 0, 0);
                a10 = __builtin_amdgcn_mfma_f32_16x16x32_bf16(a1, b0, a10, 0, 0, 0);
                a11 = __builtin_amdgcn_mfma_f32_16x16x32_bf16(a1, b1, a11, 0, 0, 0);
            }
            float* rw = red + wave * 1024;
#pragma unroll
            for (int r = 0; r < 4; ++r) {
                rw[(quad * 4 + r) * 32 + lcol]           = a00[r];
                rw[(quad * 4 + r) * 32 + 16 + lcol]      = a01[r];
                rw[(16 + quad * 4 + r) * 32 + lcol]      = a10[r];
                rw[(16 + quad * 4 + r) * 32 + 16 + lcol] = a11[r];
            }
            __syncthreads();
            const float4 s0 = *(const float4*)(red + 0 * 1024 + tid * 4);
            const float4 s1 = *(const float4*)(red + 1 * 1024 + tid * 4);
            const float4 s2 = *(const float4*)(red + 2 * 1024 + tid * 4);
            const float4 s3 = *(const float4*)(red + 3 * 1024 + tid * 4);
            sum.x = (s0.x + s1.x) + (s2.x + s3.x);
            sum.y = (s0.y + s1.y) + (s2.y + s3.y);
            sum.z = (s0.z + s1.z) + (s2.z + s3.z);
            sum.w = (s0.w + s1.w) + (s2.w + s3.w);
        }
        float4 v;
        v.x = tanhf(bf16_to_f32((unsigned short)(xpu.x & 0xFFFFu)) + sum.x + b4.x);
        v.y = tanhf(bf16_to_f32((unsigned short)(xpu.x >> 16))     + sum.y + b4.y);
        v.z = tanhf(bf16_to_f32((unsigned short)(xpu.y & 0xFFFFu)) + sum.z + b4.z);
        v.w = tanhf(bf16_to_f32((unsigned short)(xpu.y >> 16))     + sum.w + b4.w);
        if (t < 255) {
            unsigned short* hc = (t & 1) ? hB : hA;
            unsigned int p0 = (unsigned int)f32_to_bf16(v.x) | ((unsigned int)f32_to_bf16(v.y) << 16);
            unsigned int p1 = (unsigned int)f32_to_bf16(v.z) | ((unsigned int)f32_to_bf16(v.w) << 16);
            uint2 pv; pv.x = p0; pv.y = p1;
            *(uint2*)(hc + (size_t)(m0 + erow) * 2048 + n0 + ecol) = pv;
            // ---- group barrier (64 blocks sharing batch group bid&3) ----
            __threadfence();       // release: flush h stores past our XCD L2
            __syncthreads();       // all waves' fences done (also guards red)
            if (tid == 0) {
                __hip_atomic_fetch_add(cnt, 1u, __ATOMIC_RELAXED, __HIP_MEMORY_SCOPE_AGENT);
                const unsigned int tgt = 64u * (unsigned int)(t + 1);
                while (__hip_atomic_load(cnt, __ATOMIC_RELAXED, __HIP_MEMORY_SCOPE_AGENT) < tgt)
                    __builtin_amdgcn_s_sleep(2);
            }
            __syncthreads();
            __threadfence();       // acquire: invalidate so fresh h is read
        } else {
            *(float4*)(out + (size_t)(m0 + erow) * 2048 + n0 + ecol) = v;
        }
    }
}

// ---------------------------------------------------------------------------
extern "C" void kernel_launch(void* const* d_in, const int* in_sizes, int n_in,
                              void* d_out, int out_size, void* d_ws, size_t ws_size,
                              hipStream_t stream) {
    const float* x     = (const float*)d_in[0];
    const float* w_in  = (const float*)d_in[1];
    const float* w_rec = (const float*)d_in[2];
    const float* bias  = (const float*)d_in[3];
    float* out = (float*)d_out;

    char* ws = (char*)d_ws;
    unsigned short* XP     = (unsigned short*)(ws);
    unsigned short* WT_in  = (unsigned short*)(ws + 134217728);
    unsigned short* WT_rec = (unsigned short*)(ws + 134217728 + 8388608);
    unsigned short* hA     = (unsigned short*)(ws + 150994944);
    unsigned short* hB     = (unsigned short*)(ws + 150994944 + 524288);
    unsigned int*   BAR    = (unsigned int*)(ws + 152043520);

    hipMemsetAsync(BAR, 0, 1024, stream);   // ws is poisoned before every call
    cvt_transpose<<<dim3(1024), dim3(256), 0, stream>>>(w_in,  WT_in);
    cvt_transpose<<<dim3(1024), dim3(256), 0, stream>>>(w_rec, WT_rec);
    xproj_gemm<<<dim3(4096), dim3(256), 0, stream>>>(x, WT_in, XP);

    void* args[] = {(void*)&XP, (void*)&WT_rec, (void*)&bias,
                    (void*)&hA, (void*)&hB, (void*)&out, (void*)&BAR};
    hipLaunchCooperativeKernel(reinterpret_cast<void*>(rnn_scan),
                               dim3(256), dim3(256), args, 0, stream);
}

// Round 3
// 3244.950 us; speedup vs baseline: 6.1620x; 3.7560x over previous
//
#include <hip/hip_runtime.h>

// T=256, B=128, H=2048. M = T*B = 32768.
// ws layout (bytes):
//   XP     @ 0          : 134217728   (xproj, bf16, [t*128+b][h])
//   WT_in  @ 134217728  : 8388608     (w_in^T bf16, [n][k])
//   WT_rec @ 142606336  : 8388608     (w_rec^T bf16, [n][k])
//   hA     @ 150994944  : 524288      (h written at even t)
//   hB     @ 151519232  : 524288      (h written at odd t)
//   BAR    @ 152043520  : 1024        (barrier counters)

typedef __bf16 bf16x8 __attribute__((ext_vector_type(8)));
typedef float f32x4 __attribute__((ext_vector_type(4)));
typedef unsigned long long ullx2 __attribute__((ext_vector_type(2)));

__device__ __forceinline__ unsigned short f32_to_bf16(float f) {
    unsigned int u = __builtin_bit_cast(unsigned int, f);
    u += 0x7FFFu + ((u >> 16) & 1u);   // round-to-nearest-even
    return (unsigned short)(u >> 16);
}
__device__ __forceinline__ float bf16_to_f32(unsigned short s) {
    unsigned int u = ((unsigned int)s) << 16;
    return __builtin_bit_cast(float, u);
}

// ---------------------------------------------------------------------------
// Kernel 1: fp32 (2048x2048, [k][n]) -> bf16 transposed ([n][k]) via LDS tile.
// ---------------------------------------------------------------------------
__global__ __launch_bounds__(256)
void cvt_transpose(const float* __restrict__ W, unsigned short* __restrict__ WT) {
    __shared__ unsigned short tile[64][68];
    const int tid = threadIdx.x;
    const int n0 = (blockIdx.x & 31) * 64;
    const int k0 = (blockIdx.x >> 5) * 64;
    const int rr = tid >> 4;
    const int cc = (tid & 15) * 4;
#pragma unroll
    for (int p = 0; p < 4; ++p) {
        const int k = rr + p * 16;
        const float4 v = *(const float4*)(W + (size_t)(k0 + k) * 2048 + n0 + cc);
        tile[cc + 0][k] = f32_to_bf16(v.x);
        tile[cc + 1][k] = f32_to_bf16(v.y);
        tile[cc + 2][k] = f32_to_bf16(v.z);
        tile[cc + 3][k] = f32_to_bf16(v.w);
    }
    __syncthreads();
#pragma unroll
    for (int p = 0; p < 4; ++p) {
        const int n = rr + p * 16;
        unsigned int lo = (unsigned int)tile[n][cc]     | ((unsigned int)tile[n][cc + 1] << 16);
        unsigned int hi = (unsigned int)tile[n][cc + 2] | ((unsigned int)tile[n][cc + 3] << 16);
        uint2 ov; ov.x = lo; ov.y = hi;
        *(uint2*)(WT + (size_t)(n0 + n) * 2048 + k0 + cc) = ov;
    }
}

// ---------------------------------------------------------------------------
// Kernel 2: xproj GEMM. C[m][n] = sum_k X[m][k] * w_in[k][n], stored bf16.
// 128x128 tile, BK=32, 4 waves each 64x64. grid 4096 x 256.
// ---------------------------------------------------------------------------
__global__ __launch_bounds__(256, 2)
void xproj_gemm(const float* __restrict__ X, const unsigned short* __restrict__ WT,
                unsigned short* __restrict__ XP) {
    __shared__ unsigned short As[128 * 32];
    __shared__ unsigned short Bs[128 * 32];
    const int tid  = threadIdx.x;
    const int bid  = blockIdx.x;
    const int m0   = (bid >> 4) * 128;
    const int n0   = (bid & 15) * 128;
    const int lane = tid & 63;
    const int wave = tid >> 6;
    const int wm   = (wave & 1) * 64;
    const int wn   = (wave >> 1) * 64;
    const int lcol = lane & 15;
    const int quad = lane >> 4;

    const int ar = tid >> 3;
    const int ac = (tid & 7) * 4;
    const int br = tid >> 1;
    const int bc = (tid & 1) * 16;

    f32x4 acc[4][4] = {};

    for (int kk = 0; kk < 2048; kk += 32) {
#pragma unroll
        for (int p = 0; p < 4; ++p) {
            const int r = ar + p * 32;
            const float4 v = *(const float4*)(X + (size_t)(m0 + r) * 2048 + kk + ac);
            unsigned int lo = (unsigned int)f32_to_bf16(v.x) | ((unsigned int)f32_to_bf16(v.y) << 16);
            unsigned int hi = (unsigned int)f32_to_bf16(v.z) | ((unsigned int)f32_to_bf16(v.w) << 16);
            uint2 w; w.x = lo; w.y = hi;
            *(uint2*)(As + r * 32 + ac) = w;
        }
        {
            const unsigned short* g = WT + (size_t)(n0 + br) * 2048 + kk + bc;
            const uint4 v0 = *(const uint4*)(g);
            const uint4 v1 = *(const uint4*)(g + 8);
            *(uint4*)(Bs + br * 32 + bc)     = v0;
            *(uint4*)(Bs + br * 32 + bc + 8) = v1;
        }
        __syncthreads();
        bf16x8 af[4], bf[4];
#pragma unroll
        for (int i = 0; i < 4; ++i)
            af[i] = __builtin_bit_cast(bf16x8, *(const uint4*)(As + (wm + i * 16 + lcol) * 32 + quad * 8));
#pragma unroll
        for (int j = 0; j < 4; ++j)
            bf[j] = __builtin_bit_cast(bf16x8, *(const uint4*)(Bs + (wn + j * 16 + lcol) * 32 + quad * 8));
#pragma unroll
        for (int i = 0; i < 4; ++i)
#pragma unroll
            for (int j = 0; j < 4; ++j)
                acc[i][j] = __builtin_amdgcn_mfma_f32_16x16x32_bf16(af[i], bf[j], acc[i][j], 0, 0, 0);
        __syncthreads();
    }
#pragma unroll
    for (int i = 0; i < 4; ++i)
#pragma unroll
        for (int j = 0; j < 4; ++j) {
            const int row = m0 + wm + i * 16 + quad * 4;
            const int col = n0 + wn + j * 16 + lcol;
#pragma unroll
            for (int r = 0; r < 4; ++r)
                XP[(size_t)(row + r) * 2048 + col] = f32_to_bf16(acc[i][j][r]);
        }
}

// ---------------------------------------------------------------------------
// Kernel 3: persistent recurrence, FENCELESS cross-XCD handoff.
// h moves through the coherent point (L3) via agent-scope RELAXED atomics
// (sc0 sc1: bypass L1/L2) — no buffer_wbl2 / buffer_inv anywhere.
// Release: store-acks drained (s_waitcnt 0) before the arrive-add.
// Acquire: readers' h loads are themselves L2-bypassing atomic loads issued
// after the poll; stale L2 lines can never be observed.
// ---------------------------------------------------------------------------
__global__ __launch_bounds__(256, 1)
void rnn_scan(const unsigned short* __restrict__ XP,
              const unsigned short* __restrict__ WT,
              const float* __restrict__ bias,
              unsigned short* __restrict__ hA,
              unsigned short* __restrict__ hB,
              float* __restrict__ out,
              unsigned int* __restrict__ bar) {
    __shared__ unsigned short Ws[32 * 2056];  // 32 cols x 2048 k, rows padded
    __shared__ float red[4 * 1024];           // 4 wave-partials of 32x32
    const int tid  = threadIdx.x;
    const int bid  = blockIdx.x;
    const int n0   = (bid >> 2) * 32;
    const int m0   = (bid & 3) * 32;
    const int lane = tid & 63;
    const int wave = tid >> 6;
    const int lcol = lane & 15;
    const int quad = lane >> 4;
    unsigned int* cnt = bar + (bid & 3) * 64;   // 256 B apart per group

    // load w_rec^T slice into LDS
    {
        const int r  = tid >> 3;
        const int ch = (tid & 7) * 256;
        const unsigned short* src = WT + (size_t)(n0 + r) * 2048 + ch;
        unsigned short* dst = Ws + r * 2056 + ch;
#pragma unroll
        for (int c = 0; c < 32; ++c)
            *(uint4*)(dst + c * 8) = *(const uint4*)(src + c * 8);
    }
    const int erow = tid >> 3;
    const int ecol = (tid & 7) * 4;
    const float4 b4 = *(const float4*)(bias + n0 + ecol);
    __syncthreads();

    const int kb = wave * 512;
    for (int t = 0; t < 256; ++t) {
        const uint2 xpu = *(const uint2*)(XP + (size_t)(t * 128 + m0 + erow) * 2048 + n0 + ecol);
        float4 sum = {0.f, 0.f, 0.f, 0.f};
        if (t > 0) {
            const unsigned short* hprev = (t & 1) ? hA : hB;
            f32x4 a00 = {}, a01 = {}, a10 = {}, a11 = {};
            const unsigned long long* a0p =
                (const unsigned long long*)(hprev + (size_t)(m0 + lcol) * 2048 + kb + quad * 8);
            const unsigned long long* a1p = a0p + 16 * 2048 / 4;   // +16 rows (ULL units)
            const unsigned short* b0p = Ws + lcol * 2056 + kb + quad * 8;
            const unsigned short* b1p = b0p + 16 * 2056;
#pragma unroll
            for (int it = 0; it < 16; ++it) {
                const int ko = it * 8;     // ULL units: 32 bf16 = 8 ULL per iter
                ullx2 u0, u1;
                u0.x = __hip_atomic_load(a0p + ko,     __ATOMIC_RELAXED, __HIP_MEMORY_SCOPE_AGENT);
                u0.y = __hip_atomic_load(a0p + ko + 1, __ATOMIC_RELAXED, __HIP_MEMORY_SCOPE_AGENT);
                u1.x = __hip_atomic_load(a1p + ko,     __ATOMIC_RELAXED, __HIP_MEMORY_SCOPE_AGENT);
                u1.y = __hip_atomic_load(a1p + ko + 1, __ATOMIC_RELAXED, __HIP_MEMORY_SCOPE_AGENT);
                bf16x8 a0 = __builtin_bit_cast(bf16x8, u0);
                bf16x8 a1 = __builtin_bit_cast(bf16x8, u1);
                bf16x8 b0 = __builtin_bit_cast(bf16x8, *(const uint4*)(b0p + it * 32));
                bf16x8 b1 = __builtin_bit_cast(bf16x8, *(const uint4*)(b1p + it * 32));
                a00 = __builtin_amdgcn_mfma_f32_16x16x32_bf16(a0, b0, a00, 0, 0, 0);
                a01 = __builtin_amdgcn_mfma_f32_16x16x32_bf16(a0, b1, a01, 0, 0, 0);
                a10 = __builtin_amdgcn_mfma_f32_16x16x32_bf16(a1, b0, a10, 0, 0, 0);
                a11 = __builtin_amdgcn_mfma_f32_16x16x32_bf16(a1, b1, a11, 0, 0, 0);
            }
            float* rw = red + wave * 1024;
#pragma unroll
            for (int r = 0; r < 4; ++r) {
                rw[(quad * 4 + r) * 32 + lcol]           = a00[r];
                rw[(quad * 4 + r) * 32 + 16 + lcol]      = a01[r];
                rw[(16 + quad * 4 + r) * 32 + lcol]      = a10[r];
                rw[(16 + quad * 4 + r) * 32 + 16 + lcol] = a11[r];
            }
            __syncthreads();
            const float4 s0 = *(const float4*)(red + 0 * 1024 + tid * 4);
            const float4 s1 = *(const float4*)(red + 1 * 1024 + tid * 4);
            const float4 s2 = *(const float4*)(red + 2 * 1024 + tid * 4);
            const float4 s3 = *(const float4*)(red + 3 * 1024 + tid * 4);
            sum.x = (s0.x + s1.x) + (s2.x + s3.x);
            sum.y = (s0.y + s1.y) + (s2.y + s3.y);
            sum.z = (s0.z + s1.z) + (s2.z + s3.z);
            sum.w = (s0.w + s1.w) + (s2.w + s3.w);
        }
        float4 v;
        v.x = tanhf(bf16_to_f32((unsigned short)(xpu.x & 0xFFFFu)) + sum.x + b4.x);
        v.y = tanhf(bf16_to_f32((unsigned short)(xpu.x >> 16))     + sum.y + b4.y);
        v.z = tanhf(bf16_to_f32((unsigned short)(xpu.y & 0xFFFFu)) + sum.z + b4.z);
        v.w = tanhf(bf16_to_f32((unsigned short)(xpu.y >> 16))     + sum.w + b4.w);
        if (t < 255) {
            unsigned short* hc = (t & 1) ? hB : hA;
            unsigned long long pv =
                  (unsigned long long)((unsigned int)f32_to_bf16(v.x) | ((unsigned int)f32_to_bf16(v.y) << 16))
                | ((unsigned long long)((unsigned int)f32_to_bf16(v.z) | ((unsigned int)f32_to_bf16(v.w) << 16)) << 32);
            __hip_atomic_store((unsigned long long*)(hc + (size_t)(m0 + erow) * 2048 + n0 + ecol),
                               pv, __ATOMIC_RELAXED, __HIP_MEMORY_SCOPE_AGENT);
            // ---- fenceless group barrier (64 blocks sharing batch group) ----
            __builtin_amdgcn_s_waitcnt(0);   // drain store acks: data at L3
            __syncthreads();                 // all waves drained (guards red too)
            if (tid == 0) {
                __hip_atomic_fetch_add(cnt, 1u, __ATOMIC_RELAXED, __HIP_MEMORY_SCOPE_AGENT);
                const unsigned int tgt = 64u * (unsigned int)(t + 1);
                while (__hip_atomic_load(cnt, __ATOMIC_RELAXED, __HIP_MEMORY_SCOPE_AGENT) < tgt)
                    __builtin_amdgcn_s_sleep(2);
            }
            __syncthreads();
            __builtin_amdgcn_fence(__ATOMIC_ACQUIRE, "workgroup");  // compiler: no load hoisting
        } else {
            *(float4*)(out + (size_t)(m0 + erow) * 2048 + n0 + ecol) = v;
        }
    }
}

// ---------------------------------------------------------------------------
extern "C" void kernel_launch(void* const* d_in, const int* in_sizes, int n_in,
                              void* d_out, int out_size, void* d_ws, size_t ws_size,
                              hipStream_t stream) {
    const float* x     = (const float*)d_in[0];
    const float* w_in  = (const float*)d_in[1];
    const float* w_rec = (const float*)d_in[2];
    const float* bias  = (const float*)d_in[3];
    float* out = (float*)d_out;

    char* ws = (char*)d_ws;
    unsigned short* XP     = (unsigned short*)(ws);
    unsigned short* WT_in  = (unsigned short*)(ws + 134217728);
    unsigned short* WT_rec = (unsigned short*)(ws + 134217728 + 8388608);
    unsigned short* hA     = (unsigned short*)(ws + 150994944);
    unsigned short* hB     = (unsigned short*)(ws + 150994944 + 524288);
    unsigned int*   BAR    = (unsigned int*)(ws + 152043520);

    hipMemsetAsync(BAR, 0, 1024, stream);
    cvt_transpose<<<dim3(1024), dim3(256), 0, stream>>>(w_in,  WT_in);
    cvt_transpose<<<dim3(1024), dim3(256), 0, stream>>>(w_rec, WT_rec);
    xproj_gemm<<<dim3(4096), dim3(256), 0, stream>>>(x, WT_in, XP);

    void* args[] = {(void*)&XP, (void*)&WT_rec, (void*)&bias,
                    (void*)&hA, (void*)&hB, (void*)&out, (void*)&BAR};
    hipLaunchCooperativeKernel(reinterpret_cast<void*>(rnn_scan),
                               dim3(256), dim3(256), args, 0, stream);
}